// Round 27
// baseline (646.745 us; speedup 1.0000x reference)
//
#include <hip/hip_runtime.h>
#include <math.h>

#define B 4
#define C 200
#define H 128
#define W 128
#define N 16384   // H*W
#define K 256
#define ITERS 5
#define FACT 1.25f   // COMPACTNESS / S = 10 / 8
#define NT 32        // split-K n-tiles for the update GEMM (512 n each)
#define NTM 128      // n-tiles for k_mass (128 n each)
#define CPAD 208     // c padded to 13*16 for MFMA update partials
#define CP2  224     // c padded to 7*32 for bf16 operand buffers

typedef __attribute__((ext_vector_type(8))) __bf16 bf16x8;
typedef __attribute__((ext_vector_type(4))) __bf16 bf16x4;
typedef __attribute__((ext_vector_type(4))) float f32x4;

// workspace layout (floats)
#define OFF_A2    0
#define OFF_CS    (OFF_A2 + B*N)            // 65536
#define OFF_CSPAT (OFF_CS + B*K*C)          // 270336
#define OFF_B2    (OFF_CSPAT + B*K*2)       // 272384
#define OFF_SACC  (OFF_B2 + B*K)            // 273408
#define OFF_MACC  (OFF_SACC + B*K*C)        // 478208
#define OFF_SPACC (OFF_MACC + B*K)          // 479232
#define OFF_CST   (OFF_SPACC + B*K*2)       // 481280  (reserved, unused)
#define CST_SZ    (B*C*K)                   // 204800
#define OFF_PART  (OFF_CST + CST_SZ)        // 686080
#define PART_SZ   (B*NT*CPAD*K)             // 6,815,744 floats (27.3 MB)
#define OFF_MPART (OFF_PART + PART_SZ)
#define MPART_SZ  (B*NTM*3*K)               // 393,216 floats
#define WS_NEED   ((size_t)(OFF_MPART + MPART_SZ) * 4)
// fast tier: pre-converted bf16 operands for assign
#define OFF_XBF   (OFF_MPART + MPART_SZ)    // bf16 buffer, counted in floats
#define XBF_SZF   (B*N*CP2/2)               // 7,340,032 floats
#define OFF_CSBF  (OFF_XBF + XBF_SZF)
#define CSBF_SZF  (B*K*CP2/2)               // 114,688 floats
#define WS_NEED2  ((size_t)(OFF_CSBF + CSBF_SZF) * 4)
// fast2 tier: bf16 Q^T and x[c][n] for direct-global update
#define OFF_QTB   (OFF_CSBF + CSBF_SZF)
#define QTB_SZF   (B*K*N/2)                 // 8,388,608 floats (33.5 MB)
#define OFF_XB2   (OFF_QTB + QTB_SZF)
#define XB2_SZF   (B*CPAD*N/2)              // 6,815,744 floats (27.3 MB)
#define WS_NEED3  ((size_t)(OFF_XB2 + XB2_SZF) * 4)

// ---------------------------------------------------------------------------
// init: centers_spectral[b,k,c] = x[0,c,seed_n(k)]; + bf16 copy when fast
__global__ void k_init(const float* __restrict__ x, float* __restrict__ cs,
                       __bf16* __restrict__ csbf, float* __restrict__ cspat,
                       int fast) {
  int k = blockIdx.x, c = threadIdx.x;
  int i = k >> 4, j = k & 15;
  int sn = (4 + 8*i)*W + (4 + 8*j);
  if (c < C) {
    float v = x[(size_t)c*N + sn];
    for (int b = 0; b < B; ++b) {
      cs[((size_t)(b*K + k))*C + c] = v;
      if (fast) csbf[((size_t)(b*K + k))*CP2 + c] = (__bf16)v;
    }
  } else if (fast && c < CP2) {
    for (int b = 0; b < B; ++b)
      csbf[((size_t)(b*K + k))*CP2 + c] = (__bf16)0.f;
  }
  if (c == 0) {
    for (int b = 0; b < B; ++b) {
      cspat[(b*K + k)*2 + 0] = (float)(4 + 8*i);
      cspat[(b*K + k)*2 + 1] = (float)(4 + 8*j);
    }
  }
}

// one-time: x [c][n] fp32 -> xbf [n][CP2] bf16 (zero-padded c>=200)
__global__ __launch_bounds__(256) void k_prep(const float* __restrict__ x,
                                              __bf16* __restrict__ xbf) {
  __shared__ float xt[32*64];       // [ci][n]
  int bid = blockIdx.x;             // B*256
  int b  = bid >> 8;
  int n0 = (bid & 255) << 6;        // 64 n per block
  int tid = threadIdx.x;
  const float* xb = x + (size_t)b*C*N;
  __bf16* xo = xbf + ((size_t)b*N + n0)*CP2;
  for (int t = 0; t < 7; ++t) {
    int cc0 = t*32;
    __syncthreads();
    #pragma unroll
    for (int pass = 0; pass < 2; ++pass) {   // stage [32c][64n] fp32
      int f = pass*256 + tid;
      int ci = f >> 4, nq = f & 15;
      float4 v = make_float4(0.f, 0.f, 0.f, 0.f);
      if (cc0 + ci < C) v = *(const float4*)&xb[(size_t)(cc0 + ci)*N + n0 + nq*4];
      *(float4*)&xt[ci*64 + nq*4] = v;
    }
    __syncthreads();
    {                                        // transpose + cvt: [n][32c]
      int n = tid & 63, cg8 = (tid >> 6) * 8;
      bf16x8 pk;
      #pragma unroll
      for (int i = 0; i < 8; ++i) pk[i] = (__bf16)xt[(cg8 + i)*64 + n];
      *(bf16x8*)&xo[(size_t)n*CP2 + cc0 + cg8] = pk;
    }
  }
}

// one-time: x [c][n] fp32 -> xbf2 [c][n] bf16, c zero-padded to CPAD
__global__ __launch_bounds__(256) void k_prep2(const float* __restrict__ x,
                                               __bf16* __restrict__ xbf2) {
  int g = blockIdx.x * 256 + threadIdx.x;     // group of 8 n
  int per_b = CPAD * (N/8);
  int b = g / per_b;
  int rem = g - b*per_b;
  int c = rem / (N/8);
  int n = (rem - c*(N/8)) * 8;
  bf16x8 pk;
  if (c < C) {
    const float* src = &x[((size_t)b*C + c)*N + n];
    float4 v0 = *(const float4*)&src[0];
    float4 v1 = *(const float4*)&src[4];
    pk[0]=(__bf16)v0.x; pk[1]=(__bf16)v0.y; pk[2]=(__bf16)v0.z; pk[3]=(__bf16)v0.w;
    pk[4]=(__bf16)v1.x; pk[5]=(__bf16)v1.y; pk[6]=(__bf16)v1.z; pk[7]=(__bf16)v1.w;
  } else {
    #pragma unroll
    for (int i = 0; i < 8; ++i) pk[i] = (__bf16)0.f;
  }
  *(bf16x8*)&xbf2[((size_t)b*CPAD + c)*N + n] = pk;
}

// a2[b,n] = sum_c x[b,c,n]^2  (iteration-invariant)
__global__ void k_a2(const float* __restrict__ x, float* __restrict__ a2) {
  int b = blockIdx.x >> 6;
  int n = ((blockIdx.x & 63) << 8) + threadIdx.x;
  const float* xp = x + (size_t)b*C*N + n;
  float s = 0.f;
  #pragma unroll 8
  for (int c = 0; c < C; ++c) { float v = xp[(size_t)c*N]; s += v*v; }
  a2[b*N + n] = s;
}

// b2[b,k] = sum_c cs[b,k,c]^2  (once pre-loop; k_final updates after)
__global__ void k_b2(const float* __restrict__ cs, float* __restrict__ b2) {
  int bk = blockIdx.x;
  const float* p = cs + (size_t)bk*C;
  float s = 0.f;
  for (int c = threadIdx.x; c < C; c += 64) { float v = p[c]; s += v*v; }
  for (int off = 32; off > 0; off >>= 1) s += __shfl_down(s, off);
  if (threadIdx.x == 0) b2[bk] = s;
}

// ---------------------------------------------------------------------------
// assignment v15 (fast tier): direct-global MFMA + no-max softmax; when wq,
// also emits Q^T bf16 (qtb[k][n]) for the direct-global update kernel.
__global__ __launch_bounds__(512, 2) void k_assign2(
    const __bf16* __restrict__ xbf, const __bf16* __restrict__ csbf,
    const float* __restrict__ cspat, const float* __restrict__ b2,
    const float* __restrict__ a2, float* __restrict__ Q,
    __bf16* __restrict__ qtb, int wq) {
  __shared__ float b2s[K], cys[K], cxs[K];   // 3072 B
  __shared__ float a2s[128];         // 512 B
  __shared__ float redw[8*128];      // 4096 B
  __shared__ float redf[128];        // 512 B

  int b   = blockIdx.x >> 7;
  int n0  = (blockIdx.x & 127) << 7;
  int tid = threadIdx.x;
  int lane = tid & 63;
  int lr = lane & 15;
  int lg = lane >> 4;
  int w  = tid >> 6;

  if (tid < K) {
    b2s[tid] = b2[b*K + tid];
    cys[tid] = cspat[(b*K + tid)*2 + 0];
    cxs[tid] = cspat[(b*K + tid)*2 + 1];
  }
  if (tid < 128) a2s[tid] = a2[b*N + n0 + tid];
  __syncthreads();   // init visible before epilogue reads

  f32x4 acc[16];
  #pragma unroll
  for (int i = 0; i < 16; ++i) acc[i] = (f32x4){0.f, 0.f, 0.f, 0.f};

  const __bf16* cb = csbf + ((size_t)b*K + (size_t)(w*32 + lr))*CP2;
  const __bf16* xb = xbf + ((size_t)(b*N + n0 + lr))*CP2;

  for (int t = 0; t < 7; ++t) {
    int cc = t*32 + lg*8;
    bf16x8 b0 = *(const bf16x8*)&cb[cc];
    bf16x8 b1 = *(const bf16x8*)&cb[(size_t)16*CP2 + cc];
    #pragma unroll
    for (int nt = 0; nt < 8; ++nt) {
      bf16x8 av = *(const bf16x8*)&xb[(size_t)(nt*16)*CP2 + cc];
      acc[nt*2+0] = __builtin_amdgcn_mfma_f32_16x16x32_bf16(av, b0, acc[nt*2+0], 0, 0, 0);
      acc[nt*2+1] = __builtin_amdgcn_mfma_f32_16x16x32_bf16(av, b1, acc[nt*2+1], 0, 0, 0);
    }
  }

  // ---- distances -> exp(-D) directly (no max subtraction) ----
  float py = (float)(n0 >> 7);
  int k0 = w*32 + lr, k1 = k0 + 16;
  float b2v0 = b2s[k0], b2v1 = b2s[k1];
  float cx0 = cxs[k0], cx1 = cxs[k1];
  float dy0 = py - cys[k0], dy1 = py - cys[k1];
  float dyy0 = dy0*dy0, dyy1 = dy1*dy1;

  float mArr[32];
  #pragma unroll
  for (int nt = 0; nt < 8; ++nt) {
    #pragma unroll
    for (int r = 0; r < 4; ++r) {
      int pix = nt*16 + lg*4 + r;
      float a2v = a2s[pix];
      float pxv = (float)pix;
      float dx0 = pxv - cx0, dx1 = pxv - cx1;
      float d0 = sqrtf(fmaxf(a2v + b2v0 - 2.f*acc[nt*2+0][r], 1e-12f))
               + FACT*sqrtf(fmaxf(dyy0 + dx0*dx0, 1e-12f));
      float d1 = sqrtf(fmaxf(a2v + b2v1 - 2.f*acc[nt*2+1][r], 1e-12f))
               + FACT*sqrtf(fmaxf(dyy1 + dx1*dx1, 1e-12f));
      float e0 = __expf(-d0);
      float e1 = __expf(-d1);
      acc[nt*2+0][r] = e0;
      acc[nt*2+1][r] = e1;
      float s = e0 + e1;
      s += __shfl_xor(s, 1);
      s += __shfl_xor(s, 2);
      s += __shfl_xor(s, 4);
      s += __shfl_xor(s, 8);
      mArr[nt*4+r] = s;
    }
  }
  if (lr == 0) {
    #pragma unroll
    for (int nt = 0; nt < 8; ++nt)
      #pragma unroll
      for (int r = 0; r < 4; ++r)
        redw[w*128 + nt*16 + lg*4 + r] = mArr[nt*4+r];
  }
  __syncthreads();
  if (tid < 128) {
    float s = redw[tid];
    #pragma unroll
    for (int g = 1; g < 8; ++g) s += redw[g*128 + tid];
    redf[tid] = 1.f / s;
  }
  __syncthreads();
  float* Qb = Q + ((size_t)(b*N + n0))*K;
  __bf16* qt0 = qtb + ((size_t)b*K + k0)*N + n0;
  __bf16* qt1 = qtb + ((size_t)b*K + k1)*N + n0;
  #pragma unroll
  for (int nt = 0; nt < 8; ++nt) {
    bf16x4 p0, p1;
    #pragma unroll
    for (int r = 0; r < 4; ++r) {
      int pix = nt*16 + lg*4 + r;
      float inv = redf[pix];
      float f0 = acc[nt*2+0][r] * inv;
      float f1 = acc[nt*2+1][r] * inv;
      Qb[(size_t)pix*K + k0] = f0;
      Qb[(size_t)pix*K + k1] = f1;
      p0[r] = (__bf16)f0;
      p1[r] = (__bf16)f1;
    }
    if (wq) {
      *(bf16x4*)&qt0[nt*16 + lg*4] = p0;
      *(bf16x4*)&qt1[nt*16 + lg*4] = p1;
    }
  }
}

// ---------------------------------------------------------------------------
// assignment v11 (fallback tier): converts per-chunk via LDS.
__global__ __launch_bounds__(512, 2) void k_assign(
    const float* __restrict__ x, const float* __restrict__ cs,
    const float* __restrict__ cspat, const float* __restrict__ b2,
    const float* __restrict__ a2, float* __restrict__ Q) {
  __shared__ __bf16 cs_lds[K*40];
  __shared__ __bf16 x_lds[128*40];
  __shared__ float b2s[K], cys[K], cxs[K];
  __shared__ float a2s[128];
  __shared__ float redw[8*128];
  __shared__ float redf[128];

  int b   = blockIdx.x >> 7;
  int n0  = (blockIdx.x & 127) << 7;
  int tid = threadIdx.x;
  int lane = tid & 63;
  int lr = lane & 15;
  int lg = lane >> 4;
  int w  = tid >> 6;

  if (tid < K) {
    b2s[tid] = b2[b*K + tid];
    cys[tid] = cspat[(b*K + tid)*2 + 0];
    cxs[tid] = cspat[(b*K + tid)*2 + 1];
  }
  if (tid < 128) a2s[tid] = a2[b*N + n0 + tid];

  f32x4 acc[16];
  #pragma unroll
  for (int i = 0; i < 16; ++i) acc[i] = (f32x4){0.f, 0.f, 0.f, 0.f};

  const float* xb = x + (size_t)b*C*N;
  const float* cb = cs + (size_t)b*K*C;

  for (int t = 0; t < 7; ++t) {
    int cc0 = t * 32;
    __syncthreads();
    #pragma unroll
    for (int pass = 0; pass < 4; ++pass) {
      int f = pass*512 + tid;
      int k = f >> 3, c4 = (f & 7) * 4;
      float4 v = make_float4(0.f, 0.f, 0.f, 0.f);
      if (cc0 + c4 < 200) v = *(const float4*)&cb[(size_t)k*C + cc0 + c4];
      __bf16* d = &cs_lds[k*40 + c4];
      d[0] = (__bf16)v.x; d[1] = (__bf16)v.y;
      d[2] = (__bf16)v.z; d[3] = (__bf16)v.w;
    }
    #pragma unroll
    for (int pass = 0; pass < 8; ++pass) {
      int idx = pass*512 + tid;
      int ci = idx >> 7, p = idx & 127;
      float xv = (cc0 + ci < 200) ? xb[(size_t)(cc0 + ci)*N + n0 + p] : 0.f;
      x_lds[p*40 + ci] = (__bf16)xv;
    }
    __syncthreads();
    const __bf16* bbase = &cs_lds[(w*32 + lr)*40 + lg*8];
    bf16x8 b0 = *(const bf16x8*)bbase;
    bf16x8 b1 = *(const bf16x8*)(bbase + 16*40);
    const __bf16* abase = &x_lds[lr*40 + lg*8];
    #pragma unroll
    for (int nt = 0; nt < 8; ++nt) {
      bf16x8 av = *(const bf16x8*)(abase + nt*16*40);
      acc[nt*2+0] = __builtin_amdgcn_mfma_f32_16x16x32_bf16(av, b0, acc[nt*2+0], 0, 0, 0);
      acc[nt*2+1] = __builtin_amdgcn_mfma_f32_16x16x32_bf16(av, b1, acc[nt*2+1], 0, 0, 0);
    }
  }

  float py = (float)(n0 >> 7);
  float mArr[32];
  #pragma unroll
  for (int nt = 0; nt < 8; ++nt) {
    #pragma unroll
    for (int r = 0; r < 4; ++r) {
      int pix = nt*16 + lg*4 + r;
      float a2v = a2s[pix];
      float pxv = (float)pix;
      float dmin = 1e30f;
      #pragma unroll
      for (int j = 0; j < 2; ++j) {
        int k = w*32 + j*16 + lr;
        float ab = acc[nt*2+j][r];
        float dy = py - cys[k];
        float dx = pxv - cxs[k];
        float d = sqrtf(fmaxf(a2v + b2s[k] - 2.f*ab, 1e-12f))
                + FACT*sqrtf(fmaxf(dy*dy + dx*dx, 1e-12f));
        acc[nt*2+j][r] = d;
        dmin = fminf(dmin, d);
      }
      mArr[nt*4+r] = dmin;
    }
  }
  #pragma unroll
  for (int i = 0; i < 32; ++i) {
    float m = mArr[i];
    m = fminf(m, __shfl_xor(m, 1));
    m = fminf(m, __shfl_xor(m, 2));
    m = fminf(m, __shfl_xor(m, 4));
    m = fminf(m, __shfl_xor(m, 8));
    mArr[i] = m;
  }
  if (lr == 0) {
    #pragma unroll
    for (int nt = 0; nt < 8; ++nt)
      #pragma unroll
      for (int r = 0; r < 4; ++r)
        redw[w*128 + nt*16 + lg*4 + r] = mArr[nt*4+r];
  }
  __syncthreads();
  if (tid < 128) {
    float m = redw[tid];
    #pragma unroll
    for (int g = 1; g < 8; ++g) m = fminf(m, redw[g*128 + tid]);
    redf[tid] = m;
  }
  __syncthreads();
  #pragma unroll
  for (int nt = 0; nt < 8; ++nt) {
    #pragma unroll
    for (int r = 0; r < 4; ++r) {
      int pix = nt*16 + lg*4 + r;
      float mnv = redf[pix];
      float s = 0.f;
      #pragma unroll
      for (int j = 0; j < 2; ++j) {
        float e = __expf(mnv - acc[nt*2+j][r]);
        acc[nt*2+j][r] = e;
        s += e;
      }
      s += __shfl_xor(s, 1);
      s += __shfl_xor(s, 2);
      s += __shfl_xor(s, 4);
      s += __shfl_xor(s, 8);
      mArr[nt*4+r] = s;
    }
  }
  if (lr == 0) {
    #pragma unroll
    for (int nt = 0; nt < 8; ++nt)
      #pragma unroll
      for (int r = 0; r < 4; ++r)
        redw[w*128 + nt*16 + lg*4 + r] = mArr[nt*4+r];
  }
  __syncthreads();
  if (tid < 128) {
    float s = redw[tid];
    #pragma unroll
    for (int g = 1; g < 8; ++g) s += redw[g*128 + tid];
    redf[tid] = 1.f / s;
  }
  __syncthreads();
  float* Qb = Q + ((size_t)(b*N + n0))*K;
  #pragma unroll
  for (int nt = 0; nt < 8; ++nt) {
    #pragma unroll
    for (int r = 0; r < 4; ++r) {
      int pix = nt*16 + lg*4 + r;
      float inv = redf[pix];
      #pragma unroll
      for (int j = 0; j < 2; ++j) {
        int k = w*32 + j*16 + lr;
        Qb[(size_t)pix*K + k] = acc[nt*2+j][r] * inv;
      }
    }
  }
}

// ---------------------------------------------------------------------------
// update v10.1 (fast2): DIRECT-GLOBAL MFMA with c-bounds FIXED.
// A = qtb rows k, B = xbf2 rows c, bf16 n-contiguous. Per chunk: 8 b128
// loads + 16 MFMA; no LDS/barriers. For cg=3, B rows >= CPAD are clamped
// (loads stay in-bounds) and their outputs discarded at the store guard.
__global__ __launch_bounds__(256) void k_update5(
    const __bf16* __restrict__ qtb, const __bf16* __restrict__ xbf2,
    float* __restrict__ part) {
  int bid = blockIdx.x;             // B*4*NT = 512
  int b   = bid >> 7;
  int rem = bid & 127;
  int cg  = rem >> 5;               // 0..3
  int nt  = rem & 31;
  int tid = threadIdx.x;
  int lane = tid & 63, lr = lane & 15, lg = lane >> 4;
  int w   = tid >> 6;               // k-quarter
  int c0  = cg * 64;

  f32x4 acc[16];
  #pragma unroll
  for (int i = 0; i < 16; ++i) acc[i] = (f32x4){0.f, 0.f, 0.f, 0.f};

  const __bf16* qb = qtb + ((size_t)b*K + (size_t)(w*64 + lr))*N;
  // clamp B row indices so loads stay in-bounds; clamped rows' outputs
  // are discarded by the store guard below (only cg=3, u>=1 clamp).
  int cr0 = c0 + lr;                              // <= 207, always valid
  int cr1 = min(c0 + 16 + lr, CPAD - 1);
  int cr2 = min(c0 + 32 + lr, CPAD - 1);
  int cr3 = min(c0 + 48 + lr, CPAD - 1);
  const __bf16* xb0 = xbf2 + ((size_t)b*CPAD + cr0)*N;
  const __bf16* xb1 = xbf2 + ((size_t)b*CPAD + cr1)*N;
  const __bf16* xb2 = xbf2 + ((size_t)b*CPAD + cr2)*N;
  const __bf16* xb3 = xbf2 + ((size_t)b*CPAD + cr3)*N;

  for (int ch = 0; ch < 16; ++ch) {
    int nb = nt*512 + ch*32 + lg*8;
    bf16x8 A0 = *(const bf16x8*)&qb[nb];
    bf16x8 A1 = *(const bf16x8*)&qb[(size_t)16*N + nb];
    bf16x8 A2 = *(const bf16x8*)&qb[(size_t)32*N + nb];
    bf16x8 A3 = *(const bf16x8*)&qb[(size_t)48*N + nb];
    bf16x8 B0 = *(const bf16x8*)&xb0[nb];
    bf16x8 B1 = *(const bf16x8*)&xb1[nb];
    bf16x8 B2 = *(const bf16x8*)&xb2[nb];
    bf16x8 B3 = *(const bf16x8*)&xb3[nb];
    acc[0]  = __builtin_amdgcn_mfma_f32_16x16x32_bf16(A0, B0, acc[0], 0, 0, 0);
    acc[1]  = __builtin_amdgcn_mfma_f32_16x16x32_bf16(A0, B1, acc[1], 0, 0, 0);
    acc[2]  = __builtin_amdgcn_mfma_f32_16x16x32_bf16(A0, B2, acc[2], 0, 0, 0);
    acc[3]  = __builtin_amdgcn_mfma_f32_16x16x32_bf16(A0, B3, acc[3], 0, 0, 0);
    acc[4]  = __builtin_amdgcn_mfma_f32_16x16x32_bf16(A1, B0, acc[4], 0, 0, 0);
    acc[5]  = __builtin_amdgcn_mfma_f32_16x16x32_bf16(A1, B1, acc[5], 0, 0, 0);
    acc[6]  = __builtin_amdgcn_mfma_f32_16x16x32_bf16(A1, B2, acc[6], 0, 0, 0);
    acc[7]  = __builtin_amdgcn_mfma_f32_16x16x32_bf16(A1, B3, acc[7], 0, 0, 0);
    acc[8]  = __builtin_amdgcn_mfma_f32_16x16x32_bf16(A2, B0, acc[8], 0, 0, 0);
    acc[9]  = __builtin_amdgcn_mfma_f32_16x16x32_bf16(A2, B1, acc[9], 0, 0, 0);
    acc[10] = __builtin_amdgcn_mfma_f32_16x16x32_bf16(A2, B2, acc[10], 0, 0, 0);
    acc[11] = __builtin_amdgcn_mfma_f32_16x16x32_bf16(A2, B3, acc[11], 0, 0, 0);
    acc[12] = __builtin_amdgcn_mfma_f32_16x16x32_bf16(A3, B0, acc[12], 0, 0, 0);
    acc[13] = __builtin_amdgcn_mfma_f32_16x16x32_bf16(A3, B1, acc[13], 0, 0, 0);
    acc[14] = __builtin_amdgcn_mfma_f32_16x16x32_bf16(A3, B2, acc[14], 0, 0, 0);
    acc[15] = __builtin_amdgcn_mfma_f32_16x16x32_bf16(A3, B3, acc[15], 0, 0, 0);
  }

  // D row=(lg*4+r) -> k-subrow, col=lr -> c; store only valid c (< CPAD)
  float* pp = part + (size_t)(b*NT + nt) * CPAD * K;
  #pragma unroll
  for (int t = 0; t < 4; ++t) {
    #pragma unroll
    for (int u = 0; u < 4; ++u) {
      int c = c0 + u*16 + lr;
      if (c < CPAD) {
        int k = w*64 + t*16 + lg*4;
        *(f32x4*)&pp[(size_t)c*K + k] = acc[t*4+u];
      }
    }
  }
}

// ---------------------------------------------------------------------------
// update v9 (MFMA via LDS, fast tier fallback — unchanged from R22)
__global__ __launch_bounds__(256) void k_update4(
    const float* __restrict__ x, const float* __restrict__ Q,
    float* __restrict__ part) {
  __shared__ float  q32[32*256];
  __shared__ __bf16 qbf[256*40];
  __shared__ __bf16 xbf[64*40];
  int bid = blockIdx.x;
  int b   = bid >> 7;
  int rem = bid & 127;
  int cg  = rem >> 5;
  int nt  = rem & 31;
  int tid = threadIdx.x;
  int lane = tid & 63, lr = lane & 15, lg = lane >> 4;
  int w   = tid >> 6;
  int c0  = cg * 64;

  f32x4 acc[16];
  #pragma unroll
  for (int i = 0; i < 16; ++i) acc[i] = (f32x4){0.f, 0.f, 0.f, 0.f};

  const float* Qb = Q + (size_t)b*N*K;
  const float* xb = x + (size_t)b*C*N;

  for (int ch = 0; ch < 16; ++ch) {
    int nb = nt*512 + ch*32;
    __syncthreads();
    #pragma unroll
    for (int pass = 0; pass < 8; ++pass) {
      int f = pass*256 + tid;
      int n = f >> 6, k4 = f & 63;
      *(float4*)&q32[n*256 + k4*4] =
          *(const float4*)&Qb[(size_t)(nb + n)*K + k4*4];
    }
    #pragma unroll
    for (int pass = 0; pass < 2; ++pass) {
      int f = pass*256 + tid;
      int c = f >> 3, n4 = f & 7;
      int cc = c0 + c;
      float4 v = make_float4(0.f, 0.f, 0.f, 0.f);
      if (cc < 200) v = *(const float4*)&xb[(size_t)cc*N + nb + n4*4];
      __bf16* d = &xbf[c*40 + n4*4];
      d[0] = (__bf16)v.x; d[1] = (__bf16)v.y;
      d[2] = (__bf16)v.z; d[3] = (__bf16)v.w;
    }
    __syncthreads();
    {
      #pragma unroll
      for (int g = 0; g < 4; ++g) {
        bf16x8 pk;
        #pragma unroll
        for (int i = 0; i < 8; ++i)
          pk[i] = (__bf16)q32[(g*8 + i)*256 + tid];
        *(bf16x8*)&qbf[tid*40 + g*8] = pk;
      }
    }
    __syncthreads();
    const __bf16* abase = &qbf[(w*64 + lr)*40 + lg*8];
    const __bf16* bbase = &xbf[lr*40 + lg*8];
    bf16x8 A0 = *(const bf16x8*)(abase);
    bf16x8 A1 = *(const bf16x8*)(abase + 16*40);
    bf16x8 A2 = *(const bf16x8*)(abase + 32*40);
    bf16x8 A3 = *(const bf16x8*)(abase + 48*40);
    bf16x8 B0 = *(const bf16x8*)(bbase);
    bf16x8 B1 = *(const bf16x8*)(bbase + 16*40);
    bf16x8 B2 = *(const bf16x8*)(bbase + 32*40);
    bf16x8 B3 = *(const bf16x8*)(bbase + 48*40);
    acc[0]  = __builtin_amdgcn_mfma_f32_16x16x32_bf16(A0, B0, acc[0], 0, 0, 0);
    acc[1]  = __builtin_amdgcn_mfma_f32_16x16x32_bf16(A0, B1, acc[1], 0, 0, 0);
    acc[2]  = __builtin_amdgcn_mfma_f32_16x16x32_bf16(A0, B2, acc[2], 0, 0, 0);
    acc[3]  = __builtin_amdgcn_mfma_f32_16x16x32_bf16(A0, B3, acc[3], 0, 0, 0);
    acc[4]  = __builtin_amdgcn_mfma_f32_16x16x32_bf16(A1, B0, acc[4], 0, 0, 0);
    acc[5]  = __builtin_amdgcn_mfma_f32_16x16x32_bf16(A1, B1, acc[5], 0, 0, 0);
    acc[6]  = __builtin_amdgcn_mfma_f32_16x16x32_bf16(A1, B2, acc[6], 0, 0, 0);
    acc[7]  = __builtin_amdgcn_mfma_f32_16x16x32_bf16(A1, B3, acc[7], 0, 0, 0);
    acc[8]  = __builtin_amdgcn_mfma_f32_16x16x32_bf16(A2, B0, acc[8], 0, 0, 0);
    acc[9]  = __builtin_amdgcn_mfma_f32_16x16x32_bf16(A2, B1, acc[9], 0, 0, 0);
    acc[10] = __builtin_amdgcn_mfma_f32_16x16x32_bf16(A2, B2, acc[10], 0, 0, 0);
    acc[11] = __builtin_amdgcn_mfma_f32_16x16x32_bf16(A2, B3, acc[11], 0, 0, 0);
    acc[12] = __builtin_amdgcn_mfma_f32_16x16x32_bf16(A3, B0, acc[12], 0, 0, 0);
    acc[13] = __builtin_amdgcn_mfma_f32_16x16x32_bf16(A3, B1, acc[13], 0, 0, 0);
    acc[14] = __builtin_amdgcn_mfma_f32_16x16x32_bf16(A3, B2, acc[14], 0, 0, 0);
    acc[15] = __builtin_amdgcn_mfma_f32_16x16x32_bf16(A3, B3, acc[15], 0, 0, 0);
  }

  float* pp = part + (size_t)(b*NT + nt) * CPAD * K;
  #pragma unroll
  for (int t = 0; t < 4; ++t) {
    #pragma unroll
    for (int u = 0; u < 4; ++u) {
      int c = c0 + u*16 + lr;
      if (c < CPAD) {
        int k = w*64 + t*16 + lg*4;
        *(f32x4*)&pp[(size_t)c*K + k] = acc[t*4+u];
      }
    }
  }
}

// mass/spatial sums (unchanged)
__global__ __launch_bounds__(256) void k_mass(
    const float* __restrict__ Q, float* __restrict__ mpart) {
  int bid = blockIdx.x;
  int b = bid >> 7, nt = bid & 127;
  int tid = threadIdx.x;
  const float* Qb = Q + (size_t)b*N*K;
  int nbase = nt * 128;
  float mass = 0.f, sy = 0.f, sx = 0.f;
  for (int nn = 0; nn < 128; nn += 8) {
    float qv[8];
    #pragma unroll
    for (int j = 0; j < 8; ++j)
      qv[j] = Qb[(size_t)(nbase + nn + j)*K + tid];
    #pragma unroll
    for (int j = 0; j < 8; ++j) {
      int n = nbase + nn + j;
      mass += qv[j];
      sy += qv[j] * (float)(n >> 7);
      sx += qv[j] * (float)(n & 127);
    }
  }
  float* mp = mpart + (size_t)(b*NTM + nt) * 3 * K;
  mp[tid]       = mass;
  mp[K + tid]   = sy;
  mp[2*K + tid] = sx;
}

// stage 2 reduce (unchanged)
__global__ __launch_bounds__(256) void k_reduce(
    const float* __restrict__ part, const float* __restrict__ mpart,
    float* __restrict__ sacc, float* __restrict__ macc,
    float* __restrict__ spacc) {
  int bid = blockIdx.x;
  int b = bid / 200;
  int c = bid % 200;
  int tid = threadIdx.x;
  float s = 0.f;
  for (int nt = 0; nt < NT; ++nt)
    s += part[((size_t)(b*NT + nt)*CPAD + c)*K + tid];
  sacc[(size_t)(b*K + tid)*C + c] = s;
  if (c == 0) {
    float m = 0.f, yy = 0.f, xx = 0.f;
    for (int nt = 0; nt < NTM; ++nt) {
      const float* mp = mpart + (size_t)(b*NTM + nt) * 3 * K;
      m  += mp[tid];
      yy += mp[K + tid];
      xx += mp[2*K + tid];
    }
    macc[b*K + tid] = m;
    spacc[(b*K + tid)*2 + 0] = yy;
    spacc[(b*K + tid)*2 + 1] = xx;
  }
}

// atomic fallback update (unchanged)
__global__ __launch_bounds__(256, 2) void k_update(
    const float* __restrict__ x, const float* __restrict__ Q,
    float* __restrict__ sacc, float* __restrict__ macc,
    float* __restrict__ spacc) {
  __shared__ float x_lds[32*28];
  int bid = blockIdx.x;
  int b = bid >> 9;
  int rest = bid & 511;
  int ct = rest >> 6;
  int nt = rest & 63;
  int tid = threadIdx.x;
  int c0 = ct * 25;

  float acc[25];
  #pragma unroll
  for (int c = 0; c < 25; ++c) acc[c] = 0.f;
  float mass = 0.f, sy = 0.f, sx = 0.f;

  const float* xb = x + (size_t)b*C*N + (size_t)c0*N;
  const float* Qb = Q + (size_t)b*N*K;

  for (int ch = 0; ch < 8; ++ch) {
    int nb = nt*256 + ch*32;
    __syncthreads();
    #pragma unroll
    for (int pass = 0; pass < 4; ++pass) {
      int idx = pass*256 + tid;
      if (idx < 800) {
        int ci = idx >> 5, nn = idx & 31;
        x_lds[nn*28 + ci] = xb[(size_t)ci*N + nb + nn];
      }
    }
    __syncthreads();
    float py  = (float)(nb >> 7);
    float pxb = (float)(nb & 127);
    #pragma unroll
    for (int n4 = 0; n4 < 8; ++n4) {
      float qv[4];
      #pragma unroll
      for (int j = 0; j < 4; ++j)
        qv[j] = Qb[(size_t)(nb + n4*4 + j)*K + tid];
      #pragma unroll
      for (int j = 0; j < 4; ++j) {
        int nn = n4*4 + j;
        float q = qv[j];
        if (ct == 0) {
          mass += q;
          sy += q * py;
          sx += q * (pxb + (float)nn);
        }
        const float* xr = &x_lds[nn*28];
        #pragma unroll
        for (int c4 = 0; c4 < 6; ++c4) {
          float4 xv = *(const float4*)&xr[c4*4];
          acc[c4*4+0] = fmaf(q, xv.x, acc[c4*4+0]);
          acc[c4*4+1] = fmaf(q, xv.y, acc[c4*4+1]);
          acc[c4*4+2] = fmaf(q, xv.z, acc[c4*4+2]);
          acc[c4*4+3] = fmaf(q, xv.w, acc[c4*4+3]);
        }
        acc[24] = fmaf(q, xr[24], acc[24]);
      }
    }
  }
  float* sp = sacc + ((size_t)(b*K + tid))*C + c0;
  #pragma unroll
  for (int c = 0; c < 25; ++c) atomicAdd(&sp[c], acc[c]);
  if (ct == 0) {
    atomicAdd(&macc[b*K + tid], mass);
    atomicAdd(&spacc[(b*K + tid)*2 + 0], sy);
    atomicAdd(&spacc[(b*K + tid)*2 + 1], sx);
  }
}

// finalize: divide by mass; write centers (fp32 + bf16) + b2 for next iter
__global__ void k_final(const float* __restrict__ sacc, const float* __restrict__ macc,
                        const float* __restrict__ spacc, float* __restrict__ cs,
                        __bf16* __restrict__ csbf, float* __restrict__ cspat,
                        float* __restrict__ b2, float* __restrict__ outc,
                        int last, int fast) {
  __shared__ float red[256];
  int bk = blockIdx.x;
  int c = threadIdx.x;
  float inv = 1.f / (macc[bk] + 1e-6f);
  float v = 0.f;
  if (c < C) {
    v = sacc[(size_t)bk*C + c] * inv;
    cs[(size_t)bk*C + c] = v;
    if (fast) csbf[(size_t)bk*CP2 + c] = (__bf16)v;
    if (last) outc[(size_t)bk*C + c] = v;
  } else if (c == C) {
    cspat[bk*2 + 0] = spacc[bk*2 + 0] * inv;
  } else if (c == C + 1) {
    cspat[bk*2 + 1] = spacc[bk*2 + 1] * inv;
  }
  red[c] = v * v;
  __syncthreads();
  for (int off = 128; off > 0; off >>= 1) {
    if (c < off) red[c] += red[c + off];
    __syncthreads();
  }
  if (c == 0) b2[bk] = red[0];
}

extern "C" void kernel_launch(void* const* d_in, const int* in_sizes, int n_in,
                              void* d_out, int out_size, void* d_ws, size_t ws_size,
                              hipStream_t stream) {
  const float* x = (const float*)d_in[0];
  float* out = (float*)d_out;
  float* ws  = (float*)d_ws;
  float* a2    = ws + OFF_A2;
  float* cs    = ws + OFF_CS;
  float* cspat = ws + OFF_CSPAT;
  float* b2    = ws + OFF_B2;
  float* sacc  = ws + OFF_SACC;
  float* macc  = ws + OFF_MACC;
  float* spacc = ws + OFF_SPACC;
  float* part  = ws + OFF_PART;
  float* mpart = ws + OFF_MPART;
  __bf16* xbf  = (__bf16*)(ws + OFF_XBF);
  __bf16* csbf = (__bf16*)(ws + OFF_CSBF);
  __bf16* qtb  = (__bf16*)(ws + OFF_QTB);
  __bf16* xbf2 = (__bf16*)(ws + OFF_XB2);
  float* outc  = out + (size_t)B*N*K;
  int split = (ws_size >= WS_NEED) ? 1 : 0;
  int fast  = (ws_size >= WS_NEED2) ? 1 : 0;
  int fast2 = (ws_size >= WS_NEED3) ? 1 : 0;

  hipLaunchKernelGGL(k_init, dim3(K), dim3(256), 0, stream, x, cs, csbf, cspat, fast);
  hipLaunchKernelGGL(k_a2, dim3(B*64), dim3(256), 0, stream, x, a2);
  hipLaunchKernelGGL(k_b2, dim3(B*K), dim3(64), 0, stream, cs, b2);
  if (fast)
    hipLaunchKernelGGL(k_prep, dim3(B*256), dim3(256), 0, stream, x, xbf);
  if (fast2)
    hipLaunchKernelGGL(k_prep2, dim3(B*CPAD*N/8/256), dim3(256), 0, stream, x, xbf2);
  for (int it = 0; it < ITERS; ++it) {
    if (fast)
      hipLaunchKernelGGL(k_assign2, dim3(B*128), dim3(512), 0, stream,
                         xbf, csbf, cspat, b2, a2, out, qtb, fast2);
    else
      hipLaunchKernelGGL(k_assign, dim3(B*128), dim3(512), 0, stream,
                         x, cs, cspat, b2, a2, out);
    if (split) {
      if (fast2)
        hipLaunchKernelGGL(k_update5, dim3(B*4*NT), dim3(256), 0, stream,
                           qtb, xbf2, part);
      else
        hipLaunchKernelGGL(k_update4, dim3(B*4*NT), dim3(256), 0, stream,
                           x, out, part);
      hipLaunchKernelGGL(k_mass, dim3(B*NTM), dim3(256), 0, stream,
                         out, mpart);
      hipLaunchKernelGGL(k_reduce, dim3(B*200), dim3(256), 0, stream,
                         part, mpart, sacc, macc, spacc);
    } else {
      hipMemsetAsync(sacc, 0, (size_t)(B*K*C + B*K + B*K*2)*sizeof(float), stream);
      hipLaunchKernelGGL(k_update, dim3(B*512), dim3(256), 0, stream,
                         x, out, sacc, macc, spacc);
    }
    hipLaunchKernelGGL(k_final, dim3(B*K), dim3(256), 0, stream,
                       sacc, macc, spacc, cs, csbf, cspat, b2, outc,
                       (it == ITERS-1) ? 1 : 0, fast);
  }
}

// Round 28
// 537.760 us; speedup vs baseline: 1.2027x; 1.2027x over previous
//
#include <hip/hip_runtime.h>
#include <math.h>

#define B 4
#define C 200
#define H 128
#define W 128
#define N 16384   // H*W
#define K 256
#define ITERS 5
#define FACT 1.25f   // COMPACTNESS / S = 10 / 8
#define NT 32        // split-K n-tiles for the update GEMM (512 n each)
#define NTM 128      // n-tiles for k_mass (128 n each)
#define CPAD 208     // c padded to 13*16 for MFMA update partials
#define CP2  224     // c padded to 7*32 for bf16 operand buffers

typedef __attribute__((ext_vector_type(8))) __bf16 bf16x8;
typedef __attribute__((ext_vector_type(4))) __bf16 bf16x4;
typedef __attribute__((ext_vector_type(4))) float f32x4;

// workspace layout (floats)
#define OFF_A2    0
#define OFF_CS    (OFF_A2 + B*N)            // 65536
#define OFF_CSPAT (OFF_CS + B*K*C)          // 270336
#define OFF_B2    (OFF_CSPAT + B*K*2)       // 272384
#define OFF_SACC  (OFF_B2 + B*K)            // 273408
#define OFF_MACC  (OFF_SACC + B*K*C)        // 478208
#define OFF_SPACC (OFF_MACC + B*K)          // 479232
#define OFF_CST   (OFF_SPACC + B*K*2)       // 481280  (reserved, unused)
#define CST_SZ    (B*C*K)                   // 204800
#define OFF_PART  (OFF_CST + CST_SZ)        // 686080
#define PART_SZ   (B*NT*CPAD*K)             // 6,815,744 floats (27.3 MB)
#define OFF_MPART (OFF_PART + PART_SZ)
#define MPART_SZ  (B*NTM*3*K)               // 393,216 floats
#define WS_NEED   ((size_t)(OFF_MPART + MPART_SZ) * 4)
// fast tier: pre-converted bf16 operands for assign
#define OFF_XBF   (OFF_MPART + MPART_SZ)    // bf16 buffer, counted in floats
#define XBF_SZF   (B*N*CP2/2)               // 7,340,032 floats
#define OFF_CSBF  (OFF_XBF + XBF_SZF)
#define CSBF_SZF  (B*K*CP2/2)               // 114,688 floats
#define WS_NEED2  ((size_t)(OFF_CSBF + CSBF_SZF) * 4)
// fast2 tier: bf16 Q^T and x[c][n] for direct-global update
#define OFF_QTB   (OFF_CSBF + CSBF_SZF)
#define QTB_SZF   (B*K*N/2)                 // 8,388,608 floats (33.5 MB)
#define OFF_XB2   (OFF_QTB + QTB_SZF)
#define XB2_SZF   (B*CPAD*N/2)              // 6,815,744 floats (27.3 MB)
#define WS_NEED3  ((size_t)(OFF_XB2 + XB2_SZF) * 4)

// ---------------------------------------------------------------------------
// init: centers_spectral[b,k,c] = x[0,c,seed_n(k)]; + bf16 copy when fast
__global__ void k_init(const float* __restrict__ x, float* __restrict__ cs,
                       __bf16* __restrict__ csbf, float* __restrict__ cspat,
                       int fast) {
  int k = blockIdx.x, c = threadIdx.x;
  int i = k >> 4, j = k & 15;
  int sn = (4 + 8*i)*W + (4 + 8*j);
  if (c < C) {
    float v = x[(size_t)c*N + sn];
    for (int b = 0; b < B; ++b) {
      cs[((size_t)(b*K + k))*C + c] = v;
      if (fast) csbf[((size_t)(b*K + k))*CP2 + c] = (__bf16)v;
    }
  } else if (fast && c < CP2) {
    for (int b = 0; b < B; ++b)
      csbf[((size_t)(b*K + k))*CP2 + c] = (__bf16)0.f;
  }
  if (c == 0) {
    for (int b = 0; b < B; ++b) {
      cspat[(b*K + k)*2 + 0] = (float)(4 + 8*i);
      cspat[(b*K + k)*2 + 1] = (float)(4 + 8*j);
    }
  }
}

// one-time: x [c][n] fp32 -> xbf [n][CP2] bf16 (zero-padded c>=200)
__global__ __launch_bounds__(256) void k_prep(const float* __restrict__ x,
                                              __bf16* __restrict__ xbf) {
  __shared__ float xt[32*64];       // [ci][n]
  int bid = blockIdx.x;             // B*256
  int b  = bid >> 8;
  int n0 = (bid & 255) << 6;        // 64 n per block
  int tid = threadIdx.x;
  const float* xb = x + (size_t)b*C*N;
  __bf16* xo = xbf + ((size_t)b*N + n0)*CP2;
  for (int t = 0; t < 7; ++t) {
    int cc0 = t*32;
    __syncthreads();
    #pragma unroll
    for (int pass = 0; pass < 2; ++pass) {   // stage [32c][64n] fp32
      int f = pass*256 + tid;
      int ci = f >> 4, nq = f & 15;
      float4 v = make_float4(0.f, 0.f, 0.f, 0.f);
      if (cc0 + ci < C) v = *(const float4*)&xb[(size_t)(cc0 + ci)*N + n0 + nq*4];
      *(float4*)&xt[ci*64 + nq*4] = v;
    }
    __syncthreads();
    {                                        // transpose + cvt: [n][32c]
      int n = tid & 63, cg8 = (tid >> 6) * 8;
      bf16x8 pk;
      #pragma unroll
      for (int i = 0; i < 8; ++i) pk[i] = (__bf16)xt[(cg8 + i)*64 + n];
      *(bf16x8*)&xo[(size_t)n*CP2 + cc0 + cg8] = pk;
    }
  }
}

// one-time: x [c][n] fp32 -> xbf2 [c][n] bf16, with SYNTHETIC channels:
// c=200 -> 1.0 (mass), c=201 -> y(n), c=202 -> x(n); c>=203 zero.
// (y,x coords <= 127 are exactly representable in bf16.)
__global__ __launch_bounds__(256) void k_prep2(const float* __restrict__ x,
                                               __bf16* __restrict__ xbf2) {
  int g = blockIdx.x * 256 + threadIdx.x;     // group of 8 n
  int per_b = CPAD * (N/8);
  int b = g / per_b;
  int rem = g - b*per_b;
  int c = rem / (N/8);
  int n = (rem - c*(N/8)) * 8;
  bf16x8 pk;
  if (c < C) {
    const float* src = &x[((size_t)b*C + c)*N + n];
    float4 v0 = *(const float4*)&src[0];
    float4 v1 = *(const float4*)&src[4];
    pk[0]=(__bf16)v0.x; pk[1]=(__bf16)v0.y; pk[2]=(__bf16)v0.z; pk[3]=(__bf16)v0.w;
    pk[4]=(__bf16)v1.x; pk[5]=(__bf16)v1.y; pk[6]=(__bf16)v1.z; pk[7]=(__bf16)v1.w;
  } else if (c == 200) {
    #pragma unroll
    for (int i = 0; i < 8; ++i) pk[i] = (__bf16)1.0f;
  } else if (c == 201) {
    float py = (float)(n >> 7);               // constant within 8-group
    #pragma unroll
    for (int i = 0; i < 8; ++i) pk[i] = (__bf16)py;
  } else if (c == 202) {
    #pragma unroll
    for (int i = 0; i < 8; ++i) pk[i] = (__bf16)(float)((n & 127) + i);
  } else {
    #pragma unroll
    for (int i = 0; i < 8; ++i) pk[i] = (__bf16)0.f;
  }
  *(bf16x8*)&xbf2[((size_t)b*CPAD + c)*N + n] = pk;
}

// a2[b,n] = sum_c x[b,c,n]^2  (iteration-invariant)
__global__ void k_a2(const float* __restrict__ x, float* __restrict__ a2) {
  int b = blockIdx.x >> 6;
  int n = ((blockIdx.x & 63) << 8) + threadIdx.x;
  const float* xp = x + (size_t)b*C*N + n;
  float s = 0.f;
  #pragma unroll 8
  for (int c = 0; c < C; ++c) { float v = xp[(size_t)c*N]; s += v*v; }
  a2[b*N + n] = s;
}

// b2[b,k] = sum_c cs[b,k,c]^2  (once pre-loop; k_final updates after)
__global__ void k_b2(const float* __restrict__ cs, float* __restrict__ b2) {
  int bk = blockIdx.x;
  const float* p = cs + (size_t)bk*C;
  float s = 0.f;
  for (int c = threadIdx.x; c < C; c += 64) { float v = p[c]; s += v*v; }
  for (int off = 32; off > 0; off >>= 1) s += __shfl_down(s, off);
  if (threadIdx.x == 0) b2[bk] = s;
}

// ---------------------------------------------------------------------------
// assignment v16 (fast tier): direct-global MFMA + no-max softmax.
// wq: emit Q^T bf16 (qtb). wout: emit fp32 Q (only needed on last iter in
// fast2 — nothing else reads fp32 Q there).
__global__ __launch_bounds__(512, 2) void k_assign2(
    const __bf16* __restrict__ xbf, const __bf16* __restrict__ csbf,
    const float* __restrict__ cspat, const float* __restrict__ b2,
    const float* __restrict__ a2, float* __restrict__ Q,
    __bf16* __restrict__ qtb, int wq, int wout) {
  __shared__ float b2s[K], cys[K], cxs[K];   // 3072 B
  __shared__ float a2s[128];         // 512 B
  __shared__ float redw[8*128];      // 4096 B
  __shared__ float redf[128];        // 512 B

  int b   = blockIdx.x >> 7;
  int n0  = (blockIdx.x & 127) << 7;
  int tid = threadIdx.x;
  int lane = tid & 63;
  int lr = lane & 15;
  int lg = lane >> 4;
  int w  = tid >> 6;

  if (tid < K) {
    b2s[tid] = b2[b*K + tid];
    cys[tid] = cspat[(b*K + tid)*2 + 0];
    cxs[tid] = cspat[(b*K + tid)*2 + 1];
  }
  if (tid < 128) a2s[tid] = a2[b*N + n0 + tid];
  __syncthreads();   // init visible before epilogue reads

  f32x4 acc[16];
  #pragma unroll
  for (int i = 0; i < 16; ++i) acc[i] = (f32x4){0.f, 0.f, 0.f, 0.f};

  const __bf16* cb = csbf + ((size_t)b*K + (size_t)(w*32 + lr))*CP2;
  const __bf16* xb = xbf + ((size_t)(b*N + n0 + lr))*CP2;

  for (int t = 0; t < 7; ++t) {
    int cc = t*32 + lg*8;
    bf16x8 b0 = *(const bf16x8*)&cb[cc];
    bf16x8 b1 = *(const bf16x8*)&cb[(size_t)16*CP2 + cc];
    #pragma unroll
    for (int nt = 0; nt < 8; ++nt) {
      bf16x8 av = *(const bf16x8*)&xb[(size_t)(nt*16)*CP2 + cc];
      acc[nt*2+0] = __builtin_amdgcn_mfma_f32_16x16x32_bf16(av, b0, acc[nt*2+0], 0, 0, 0);
      acc[nt*2+1] = __builtin_amdgcn_mfma_f32_16x16x32_bf16(av, b1, acc[nt*2+1], 0, 0, 0);
    }
  }

  // ---- distances -> exp(-D) directly (no max subtraction) ----
  float py = (float)(n0 >> 7);
  int k0 = w*32 + lr, k1 = k0 + 16;
  float b2v0 = b2s[k0], b2v1 = b2s[k1];
  float cx0 = cxs[k0], cx1 = cxs[k1];
  float dy0 = py - cys[k0], dy1 = py - cys[k1];
  float dyy0 = dy0*dy0, dyy1 = dy1*dy1;

  float mArr[32];
  #pragma unroll
  for (int nt = 0; nt < 8; ++nt) {
    #pragma unroll
    for (int r = 0; r < 4; ++r) {
      int pix = nt*16 + lg*4 + r;
      float a2v = a2s[pix];
      float pxv = (float)pix;
      float dx0 = pxv - cx0, dx1 = pxv - cx1;
      float d0 = sqrtf(fmaxf(a2v + b2v0 - 2.f*acc[nt*2+0][r], 1e-12f))
               + FACT*sqrtf(fmaxf(dyy0 + dx0*dx0, 1e-12f));
      float d1 = sqrtf(fmaxf(a2v + b2v1 - 2.f*acc[nt*2+1][r], 1e-12f))
               + FACT*sqrtf(fmaxf(dyy1 + dx1*dx1, 1e-12f));
      float e0 = __expf(-d0);
      float e1 = __expf(-d1);
      acc[nt*2+0][r] = e0;
      acc[nt*2+1][r] = e1;
      float s = e0 + e1;
      s += __shfl_xor(s, 1);
      s += __shfl_xor(s, 2);
      s += __shfl_xor(s, 4);
      s += __shfl_xor(s, 8);
      mArr[nt*4+r] = s;
    }
  }
  if (lr == 0) {
    #pragma unroll
    for (int nt = 0; nt < 8; ++nt)
      #pragma unroll
      for (int r = 0; r < 4; ++r)
        redw[w*128 + nt*16 + lg*4 + r] = mArr[nt*4+r];
  }
  __syncthreads();
  if (tid < 128) {
    float s = redw[tid];
    #pragma unroll
    for (int g = 1; g < 8; ++g) s += redw[g*128 + tid];
    redf[tid] = 1.f / s;
  }
  __syncthreads();
  float* Qb = Q + ((size_t)(b*N + n0))*K;
  __bf16* qt0 = qtb + ((size_t)b*K + k0)*N + n0;
  __bf16* qt1 = qtb + ((size_t)b*K + k1)*N + n0;
  #pragma unroll
  for (int nt = 0; nt < 8; ++nt) {
    bf16x4 p0, p1;
    #pragma unroll
    for (int r = 0; r < 4; ++r) {
      int pix = nt*16 + lg*4 + r;
      float inv = redf[pix];
      float f0 = acc[nt*2+0][r] * inv;
      float f1 = acc[nt*2+1][r] * inv;
      if (wout) {
        Qb[(size_t)pix*K + k0] = f0;
        Qb[(size_t)pix*K + k1] = f1;
      }
      p0[r] = (__bf16)f0;
      p1[r] = (__bf16)f1;
    }
    if (wq) {
      *(bf16x4*)&qt0[nt*16 + lg*4] = p0;
      *(bf16x4*)&qt1[nt*16 + lg*4] = p1;
    }
  }
}

// ---------------------------------------------------------------------------
// assignment v11 (fallback tier): converts per-chunk via LDS.
__global__ __launch_bounds__(512, 2) void k_assign(
    const float* __restrict__ x, const float* __restrict__ cs,
    const float* __restrict__ cspat, const float* __restrict__ b2,
    const float* __restrict__ a2, float* __restrict__ Q) {
  __shared__ __bf16 cs_lds[K*40];
  __shared__ __bf16 x_lds[128*40];
  __shared__ float b2s[K], cys[K], cxs[K];
  __shared__ float a2s[128];
  __shared__ float redw[8*128];
  __shared__ float redf[128];

  int b   = blockIdx.x >> 7;
  int n0  = (blockIdx.x & 127) << 7;
  int tid = threadIdx.x;
  int lane = tid & 63;
  int lr = lane & 15;
  int lg = lane >> 4;
  int w  = tid >> 6;

  if (tid < K) {
    b2s[tid] = b2[b*K + tid];
    cys[tid] = cspat[(b*K + tid)*2 + 0];
    cxs[tid] = cspat[(b*K + tid)*2 + 1];
  }
  if (tid < 128) a2s[tid] = a2[b*N + n0 + tid];

  f32x4 acc[16];
  #pragma unroll
  for (int i = 0; i < 16; ++i) acc[i] = (f32x4){0.f, 0.f, 0.f, 0.f};

  const float* xb = x + (size_t)b*C*N;
  const float* cb = cs + (size_t)b*K*C;

  for (int t = 0; t < 7; ++t) {
    int cc0 = t * 32;
    __syncthreads();
    #pragma unroll
    for (int pass = 0; pass < 4; ++pass) {
      int f = pass*512 + tid;
      int k = f >> 3, c4 = (f & 7) * 4;
      float4 v = make_float4(0.f, 0.f, 0.f, 0.f);
      if (cc0 + c4 < 200) v = *(const float4*)&cb[(size_t)k*C + cc0 + c4];
      __bf16* d = &cs_lds[k*40 + c4];
      d[0] = (__bf16)v.x; d[1] = (__bf16)v.y;
      d[2] = (__bf16)v.z; d[3] = (__bf16)v.w;
    }
    #pragma unroll
    for (int pass = 0; pass < 8; ++pass) {
      int idx = pass*512 + tid;
      int ci = idx >> 7, p = idx & 127;
      float xv = (cc0 + ci < 200) ? xb[(size_t)(cc0 + ci)*N + n0 + p] : 0.f;
      x_lds[p*40 + ci] = (__bf16)xv;
    }
    __syncthreads();
    const __bf16* bbase = &cs_lds[(w*32 + lr)*40 + lg*8];
    bf16x8 b0 = *(const bf16x8*)bbase;
    bf16x8 b1 = *(const bf16x8*)(bbase + 16*40);
    const __bf16* abase = &x_lds[lr*40 + lg*8];
    #pragma unroll
    for (int nt = 0; nt < 8; ++nt) {
      bf16x8 av = *(const bf16x8*)(abase + nt*16*40);
      acc[nt*2+0] = __builtin_amdgcn_mfma_f32_16x16x32_bf16(av, b0, acc[nt*2+0], 0, 0, 0);
      acc[nt*2+1] = __builtin_amdgcn_mfma_f32_16x16x32_bf16(av, b1, acc[nt*2+1], 0, 0, 0);
    }
  }

  float py = (float)(n0 >> 7);
  float mArr[32];
  #pragma unroll
  for (int nt = 0; nt < 8; ++nt) {
    #pragma unroll
    for (int r = 0; r < 4; ++r) {
      int pix = nt*16 + lg*4 + r;
      float a2v = a2s[pix];
      float pxv = (float)pix;
      float dmin = 1e30f;
      #pragma unroll
      for (int j = 0; j < 2; ++j) {
        int k = w*32 + j*16 + lr;
        float ab = acc[nt*2+j][r];
        float dy = py - cys[k];
        float dx = pxv - cxs[k];
        float d = sqrtf(fmaxf(a2v + b2s[k] - 2.f*ab, 1e-12f))
                + FACT*sqrtf(fmaxf(dy*dy + dx*dx, 1e-12f));
        acc[nt*2+j][r] = d;
        dmin = fminf(dmin, d);
      }
      mArr[nt*4+r] = dmin;
    }
  }
  #pragma unroll
  for (int i = 0; i < 32; ++i) {
    float m = mArr[i];
    m = fminf(m, __shfl_xor(m, 1));
    m = fminf(m, __shfl_xor(m, 2));
    m = fminf(m, __shfl_xor(m, 4));
    m = fminf(m, __shfl_xor(m, 8));
    mArr[i] = m;
  }
  if (lr == 0) {
    #pragma unroll
    for (int nt = 0; nt < 8; ++nt)
      #pragma unroll
      for (int r = 0; r < 4; ++r)
        redw[w*128 + nt*16 + lg*4 + r] = mArr[nt*4+r];
  }
  __syncthreads();
  if (tid < 128) {
    float m = redw[tid];
    #pragma unroll
    for (int g = 1; g < 8; ++g) m = fminf(m, redw[g*128 + tid]);
    redf[tid] = m;
  }
  __syncthreads();
  #pragma unroll
  for (int nt = 0; nt < 8; ++nt) {
    #pragma unroll
    for (int r = 0; r < 4; ++r) {
      int pix = nt*16 + lg*4 + r;
      float mnv = redf[pix];
      float s = 0.f;
      #pragma unroll
      for (int j = 0; j < 2; ++j) {
        float e = __expf(mnv - acc[nt*2+j][r]);
        acc[nt*2+j][r] = e;
        s += e;
      }
      s += __shfl_xor(s, 1);
      s += __shfl_xor(s, 2);
      s += __shfl_xor(s, 4);
      s += __shfl_xor(s, 8);
      mArr[nt*4+r] = s;
    }
  }
  if (lr == 0) {
    #pragma unroll
    for (int nt = 0; nt < 8; ++nt)
      #pragma unroll
      for (int r = 0; r < 4; ++r)
        redw[w*128 + nt*16 + lg*4 + r] = mArr[nt*4+r];
  }
  __syncthreads();
  if (tid < 128) {
    float s = redw[tid];
    #pragma unroll
    for (int g = 1; g < 8; ++g) s += redw[g*128 + tid];
    redf[tid] = 1.f / s;
  }
  __syncthreads();
  float* Qb = Q + ((size_t)(b*N + n0))*K;
  #pragma unroll
  for (int nt = 0; nt < 8; ++nt) {
    #pragma unroll
    for (int r = 0; r < 4; ++r) {
      int pix = nt*16 + lg*4 + r;
      float inv = redf[pix];
      #pragma unroll
      for (int j = 0; j < 2; ++j) {
        int k = w*32 + j*16 + lr;
        Qb[(size_t)pix*K + k] = acc[nt*2+j][r] * inv;
      }
    }
  }
}

// ---------------------------------------------------------------------------
// update v10.1 (fast2): DIRECT-GLOBAL MFMA with c-bounds guard.
// Synthetic channels in xbf2 rows 200-202 make part rows 200-202 carry
// mass/sy/sx for free.
__global__ __launch_bounds__(256) void k_update5(
    const __bf16* __restrict__ qtb, const __bf16* __restrict__ xbf2,
    float* __restrict__ part) {
  int bid = blockIdx.x;             // B*4*NT = 512
  int b   = bid >> 7;
  int rem = bid & 127;
  int cg  = rem >> 5;               // 0..3
  int nt  = rem & 31;
  int tid = threadIdx.x;
  int lane = tid & 63, lr = lane & 15, lg = lane >> 4;
  int w   = tid >> 6;               // k-quarter
  int c0  = cg * 64;

  f32x4 acc[16];
  #pragma unroll
  for (int i = 0; i < 16; ++i) acc[i] = (f32x4){0.f, 0.f, 0.f, 0.f};

  const __bf16* qb = qtb + ((size_t)b*K + (size_t)(w*64 + lr))*N;
  int cr0 = c0 + lr;                              // <= 207, always valid
  int cr1 = min(c0 + 16 + lr, CPAD - 1);
  int cr2 = min(c0 + 32 + lr, CPAD - 1);
  int cr3 = min(c0 + 48 + lr, CPAD - 1);
  const __bf16* xb0 = xbf2 + ((size_t)b*CPAD + cr0)*N;
  const __bf16* xb1 = xbf2 + ((size_t)b*CPAD + cr1)*N;
  const __bf16* xb2 = xbf2 + ((size_t)b*CPAD + cr2)*N;
  const __bf16* xb3 = xbf2 + ((size_t)b*CPAD + cr3)*N;

  for (int ch = 0; ch < 16; ++ch) {
    int nb = nt*512 + ch*32 + lg*8;
    bf16x8 A0 = *(const bf16x8*)&qb[nb];
    bf16x8 A1 = *(const bf16x8*)&qb[(size_t)16*N + nb];
    bf16x8 A2 = *(const bf16x8*)&qb[(size_t)32*N + nb];
    bf16x8 A3 = *(const bf16x8*)&qb[(size_t)48*N + nb];
    bf16x8 B0 = *(const bf16x8*)&xb0[nb];
    bf16x8 B1 = *(const bf16x8*)&xb1[nb];
    bf16x8 B2 = *(const bf16x8*)&xb2[nb];
    bf16x8 B3 = *(const bf16x8*)&xb3[nb];
    acc[0]  = __builtin_amdgcn_mfma_f32_16x16x32_bf16(A0, B0, acc[0], 0, 0, 0);
    acc[1]  = __builtin_amdgcn_mfma_f32_16x16x32_bf16(A0, B1, acc[1], 0, 0, 0);
    acc[2]  = __builtin_amdgcn_mfma_f32_16x16x32_bf16(A0, B2, acc[2], 0, 0, 0);
    acc[3]  = __builtin_amdgcn_mfma_f32_16x16x32_bf16(A0, B3, acc[3], 0, 0, 0);
    acc[4]  = __builtin_amdgcn_mfma_f32_16x16x32_bf16(A1, B0, acc[4], 0, 0, 0);
    acc[5]  = __builtin_amdgcn_mfma_f32_16x16x32_bf16(A1, B1, acc[5], 0, 0, 0);
    acc[6]  = __builtin_amdgcn_mfma_f32_16x16x32_bf16(A1, B2, acc[6], 0, 0, 0);
    acc[7]  = __builtin_amdgcn_mfma_f32_16x16x32_bf16(A1, B3, acc[7], 0, 0, 0);
    acc[8]  = __builtin_amdgcn_mfma_f32_16x16x32_bf16(A2, B0, acc[8], 0, 0, 0);
    acc[9]  = __builtin_amdgcn_mfma_f32_16x16x32_bf16(A2, B1, acc[9], 0, 0, 0);
    acc[10] = __builtin_amdgcn_mfma_f32_16x16x32_bf16(A2, B2, acc[10], 0, 0, 0);
    acc[11] = __builtin_amdgcn_mfma_f32_16x16x32_bf16(A2, B3, acc[11], 0, 0, 0);
    acc[12] = __builtin_amdgcn_mfma_f32_16x16x32_bf16(A3, B0, acc[12], 0, 0, 0);
    acc[13] = __builtin_amdgcn_mfma_f32_16x16x32_bf16(A3, B1, acc[13], 0, 0, 0);
    acc[14] = __builtin_amdgcn_mfma_f32_16x16x32_bf16(A3, B2, acc[14], 0, 0, 0);
    acc[15] = __builtin_amdgcn_mfma_f32_16x16x32_bf16(A3, B3, acc[15], 0, 0, 0);
  }

  float* pp = part + (size_t)(b*NT + nt) * CPAD * K;
  #pragma unroll
  for (int t = 0; t < 4; ++t) {
    #pragma unroll
    for (int u = 0; u < 4; ++u) {
      int c = c0 + u*16 + lr;
      if (c < CPAD) {
        int k = w*64 + t*16 + lg*4;
        *(f32x4*)&pp[(size_t)c*K + k] = acc[t*4+u];
      }
    }
  }
}

// ---------------------------------------------------------------------------
// update v9 (MFMA via LDS, fast tier fallback — unchanged)
__global__ __launch_bounds__(256) void k_update4(
    const float* __restrict__ x, const float* __restrict__ Q,
    float* __restrict__ part) {
  __shared__ float  q32[32*256];
  __shared__ __bf16 qbf[256*40];
  __shared__ __bf16 xbf[64*40];
  int bid = blockIdx.x;
  int b   = bid >> 7;
  int rem = bid & 127;
  int cg  = rem >> 5;
  int nt  = rem & 31;
  int tid = threadIdx.x;
  int lane = tid & 63, lr = lane & 15, lg = lane >> 4;
  int w   = tid >> 6;
  int c0  = cg * 64;

  f32x4 acc[16];
  #pragma unroll
  for (int i = 0; i < 16; ++i) acc[i] = (f32x4){0.f, 0.f, 0.f, 0.f};

  const float* Qb = Q + (size_t)b*N*K;
  const float* xb = x + (size_t)b*C*N;

  for (int ch = 0; ch < 16; ++ch) {
    int nb = nt*512 + ch*32;
    __syncthreads();
    #pragma unroll
    for (int pass = 0; pass < 8; ++pass) {
      int f = pass*256 + tid;
      int n = f >> 6, k4 = f & 63;
      *(float4*)&q32[n*256 + k4*4] =
          *(const float4*)&Qb[(size_t)(nb + n)*K + k4*4];
    }
    #pragma unroll
    for (int pass = 0; pass < 2; ++pass) {
      int f = pass*256 + tid;
      int c = f >> 3, n4 = f & 7;
      int cc = c0 + c;
      float4 v = make_float4(0.f, 0.f, 0.f, 0.f);
      if (cc < 200) v = *(const float4*)&xb[(size_t)cc*N + nb + n4*4];
      __bf16* d = &xbf[c*40 + n4*4];
      d[0] = (__bf16)v.x; d[1] = (__bf16)v.y;
      d[2] = (__bf16)v.z; d[3] = (__bf16)v.w;
    }
    __syncthreads();
    {
      #pragma unroll
      for (int g = 0; g < 4; ++g) {
        bf16x8 pk;
        #pragma unroll
        for (int i = 0; i < 8; ++i)
          pk[i] = (__bf16)q32[(g*8 + i)*256 + tid];
        *(bf16x8*)&qbf[tid*40 + g*8] = pk;
      }
    }
    __syncthreads();
    const __bf16* abase = &qbf[(w*64 + lr)*40 + lg*8];
    const __bf16* bbase = &xbf[lr*40 + lg*8];
    bf16x8 A0 = *(const bf16x8*)(abase);
    bf16x8 A1 = *(const bf16x8*)(abase + 16*40);
    bf16x8 A2 = *(const bf16x8*)(abase + 32*40);
    bf16x8 A3 = *(const bf16x8*)(abase + 48*40);
    bf16x8 B0 = *(const bf16x8*)(bbase);
    bf16x8 B1 = *(const bf16x8*)(bbase + 16*40);
    bf16x8 B2 = *(const bf16x8*)(bbase + 32*40);
    bf16x8 B3 = *(const bf16x8*)(bbase + 48*40);
    acc[0]  = __builtin_amdgcn_mfma_f32_16x16x32_bf16(A0, B0, acc[0], 0, 0, 0);
    acc[1]  = __builtin_amdgcn_mfma_f32_16x16x32_bf16(A0, B1, acc[1], 0, 0, 0);
    acc[2]  = __builtin_amdgcn_mfma_f32_16x16x32_bf16(A0, B2, acc[2], 0, 0, 0);
    acc[3]  = __builtin_amdgcn_mfma_f32_16x16x32_bf16(A0, B3, acc[3], 0, 0, 0);
    acc[4]  = __builtin_amdgcn_mfma_f32_16x16x32_bf16(A1, B0, acc[4], 0, 0, 0);
    acc[5]  = __builtin_amdgcn_mfma_f32_16x16x32_bf16(A1, B1, acc[5], 0, 0, 0);
    acc[6]  = __builtin_amdgcn_mfma_f32_16x16x32_bf16(A1, B2, acc[6], 0, 0, 0);
    acc[7]  = __builtin_amdgcn_mfma_f32_16x16x32_bf16(A1, B3, acc[7], 0, 0, 0);
    acc[8]  = __builtin_amdgcn_mfma_f32_16x16x32_bf16(A2, B0, acc[8], 0, 0, 0);
    acc[9]  = __builtin_amdgcn_mfma_f32_16x16x32_bf16(A2, B1, acc[9], 0, 0, 0);
    acc[10] = __builtin_amdgcn_mfma_f32_16x16x32_bf16(A2, B2, acc[10], 0, 0, 0);
    acc[11] = __builtin_amdgcn_mfma_f32_16x16x32_bf16(A2, B3, acc[11], 0, 0, 0);
    acc[12] = __builtin_amdgcn_mfma_f32_16x16x32_bf16(A3, B0, acc[12], 0, 0, 0);
    acc[13] = __builtin_amdgcn_mfma_f32_16x16x32_bf16(A3, B1, acc[13], 0, 0, 0);
    acc[14] = __builtin_amdgcn_mfma_f32_16x16x32_bf16(A3, B2, acc[14], 0, 0, 0);
    acc[15] = __builtin_amdgcn_mfma_f32_16x16x32_bf16(A3, B3, acc[15], 0, 0, 0);
  }

  float* pp = part + (size_t)(b*NT + nt) * CPAD * K;
  #pragma unroll
  for (int t = 0; t < 4; ++t) {
    #pragma unroll
    for (int u = 0; u < 4; ++u) {
      int c = c0 + u*16 + lr;
      if (c < CPAD) {
        int k = w*64 + t*16 + lg*4;
        *(f32x4*)&pp[(size_t)c*K + k] = acc[t*4+u];
      }
    }
  }
}

// mass/spatial sums (fast tier only)
__global__ __launch_bounds__(256) void k_mass(
    const float* __restrict__ Q, float* __restrict__ mpart) {
  int bid = blockIdx.x;
  int b = bid >> 7, nt = bid & 127;
  int tid = threadIdx.x;
  const float* Qb = Q + (size_t)b*N*K;
  int nbase = nt * 128;
  float mass = 0.f, sy = 0.f, sx = 0.f;
  for (int nn = 0; nn < 128; nn += 8) {
    float qv[8];
    #pragma unroll
    for (int j = 0; j < 8; ++j)
      qv[j] = Qb[(size_t)(nbase + nn + j)*K + tid];
    #pragma unroll
    for (int j = 0; j < 8; ++j) {
      int n = nbase + nn + j;
      mass += qv[j];
      sy += qv[j] * (float)(n >> 7);
      sx += qv[j] * (float)(n & 127);
    }
  }
  float* mp = mpart + (size_t)(b*NTM + nt) * 3 * K;
  mp[tid]       = mass;
  mp[K + tid]   = sy;
  mp[2*K + tid] = sx;
}

// stage 2 reduce: fast2 takes mass/sy/sx from part rows 200-202.
__global__ __launch_bounds__(256) void k_reduce(
    const float* __restrict__ part, const float* __restrict__ mpart,
    float* __restrict__ sacc, float* __restrict__ macc,
    float* __restrict__ spacc, int fast2) {
  int bid = blockIdx.x;
  int b = bid / 200;
  int c = bid % 200;
  int tid = threadIdx.x;
  float s = 0.f;
  for (int nt = 0; nt < NT; ++nt)
    s += part[((size_t)(b*NT + nt)*CPAD + c)*K + tid];
  sacc[(size_t)(b*K + tid)*C + c] = s;
  if (c == 0) {
    float m = 0.f, yy = 0.f, xx = 0.f;
    if (fast2) {
      for (int nt = 0; nt < NT; ++nt) {
        const float* pb = part + (size_t)(b*NT + nt)*CPAD*K;
        m  += pb[(size_t)200*K + tid];
        yy += pb[(size_t)201*K + tid];
        xx += pb[(size_t)202*K + tid];
      }
    } else {
      for (int nt = 0; nt < NTM; ++nt) {
        const float* mp = mpart + (size_t)(b*NTM + nt) * 3 * K;
        m  += mp[tid];
        yy += mp[K + tid];
        xx += mp[2*K + tid];
      }
    }
    macc[b*K + tid] = m;
    spacc[(b*K + tid)*2 + 0] = yy;
    spacc[(b*K + tid)*2 + 1] = xx;
  }
}

// atomic fallback update (unchanged)
__global__ __launch_bounds__(256, 2) void k_update(
    const float* __restrict__ x, const float* __restrict__ Q,
    float* __restrict__ sacc, float* __restrict__ macc,
    float* __restrict__ spacc) {
  __shared__ float x_lds[32*28];
  int bid = blockIdx.x;
  int b = bid >> 9;
  int rest = bid & 511;
  int ct = rest >> 6;
  int nt = rest & 63;
  int tid = threadIdx.x;
  int c0 = ct * 25;

  float acc[25];
  #pragma unroll
  for (int c = 0; c < 25; ++c) acc[c] = 0.f;
  float mass = 0.f, sy = 0.f, sx = 0.f;

  const float* xb = x + (size_t)b*C*N + (size_t)c0*N;
  const float* Qb = Q + (size_t)b*N*K;

  for (int ch = 0; ch < 8; ++ch) {
    int nb = nt*256 + ch*32;
    __syncthreads();
    #pragma unroll
    for (int pass = 0; pass < 4; ++pass) {
      int idx = pass*256 + tid;
      if (idx < 800) {
        int ci = idx >> 5, nn = idx & 31;
        x_lds[nn*28 + ci] = xb[(size_t)ci*N + nb + nn];
      }
    }
    __syncthreads();
    float py  = (float)(nb >> 7);
    float pxb = (float)(nb & 127);
    #pragma unroll
    for (int n4 = 0; n4 < 8; ++n4) {
      float qv[4];
      #pragma unroll
      for (int j = 0; j < 4; ++j)
        qv[j] = Qb[(size_t)(nb + n4*4 + j)*K + tid];
      #pragma unroll
      for (int j = 0; j < 4; ++j) {
        int nn = n4*4 + j;
        float q = qv[j];
        if (ct == 0) {
          mass += q;
          sy += q * py;
          sx += q * (pxb + (float)nn);
        }
        const float* xr = &x_lds[nn*28];
        #pragma unroll
        for (int c4 = 0; c4 < 6; ++c4) {
          float4 xv = *(const float4*)&xr[c4*4];
          acc[c4*4+0] = fmaf(q, xv.x, acc[c4*4+0]);
          acc[c4*4+1] = fmaf(q, xv.y, acc[c4*4+1]);
          acc[c4*4+2] = fmaf(q, xv.z, acc[c4*4+2]);
          acc[c4*4+3] = fmaf(q, xv.w, acc[c4*4+3]);
        }
        acc[24] = fmaf(q, xr[24], acc[24]);
      }
    }
  }
  float* sp = sacc + ((size_t)(b*K + tid))*C + c0;
  #pragma unroll
  for (int c = 0; c < 25; ++c) atomicAdd(&sp[c], acc[c]);
  if (ct == 0) {
    atomicAdd(&macc[b*K + tid], mass);
    atomicAdd(&spacc[(b*K + tid)*2 + 0], sy);
    atomicAdd(&spacc[(b*K + tid)*2 + 1], sx);
  }
}

// finalize: divide by mass; write centers (fp32 + bf16) + b2 for next iter
__global__ void k_final(const float* __restrict__ sacc, const float* __restrict__ macc,
                        const float* __restrict__ spacc, float* __restrict__ cs,
                        __bf16* __restrict__ csbf, float* __restrict__ cspat,
                        float* __restrict__ b2, float* __restrict__ outc,
                        int last, int fast) {
  __shared__ float red[256];
  int bk = blockIdx.x;
  int c = threadIdx.x;
  float inv = 1.f / (macc[bk] + 1e-6f);
  float v = 0.f;
  if (c < C) {
    v = sacc[(size_t)bk*C + c] * inv;
    cs[(size_t)bk*C + c] = v;
    if (fast) csbf[(size_t)bk*CP2 + c] = (__bf16)v;
    if (last) outc[(size_t)bk*C + c] = v;
  } else if (c == C) {
    cspat[bk*2 + 0] = spacc[bk*2 + 0] * inv;
  } else if (c == C + 1) {
    cspat[bk*2 + 1] = spacc[bk*2 + 1] * inv;
  }
  red[c] = v * v;
  __syncthreads();
  for (int off = 128; off > 0; off >>= 1) {
    if (c < off) red[c] += red[c + off];
    __syncthreads();
  }
  if (c == 0) b2[bk] = red[0];
}

extern "C" void kernel_launch(void* const* d_in, const int* in_sizes, int n_in,
                              void* d_out, int out_size, void* d_ws, size_t ws_size,
                              hipStream_t stream) {
  const float* x = (const float*)d_in[0];
  float* out = (float*)d_out;
  float* ws  = (float*)d_ws;
  float* a2    = ws + OFF_A2;
  float* cs    = ws + OFF_CS;
  float* cspat = ws + OFF_CSPAT;
  float* b2    = ws + OFF_B2;
  float* sacc  = ws + OFF_SACC;
  float* macc  = ws + OFF_MACC;
  float* spacc = ws + OFF_SPACC;
  float* part  = ws + OFF_PART;
  float* mpart = ws + OFF_MPART;
  __bf16* xbf  = (__bf16*)(ws + OFF_XBF);
  __bf16* csbf = (__bf16*)(ws + OFF_CSBF);
  __bf16* qtb  = (__bf16*)(ws + OFF_QTB);
  __bf16* xbf2 = (__bf16*)(ws + OFF_XB2);
  float* outc  = out + (size_t)B*N*K;
  int split = (ws_size >= WS_NEED) ? 1 : 0;
  int fast  = (ws_size >= WS_NEED2) ? 1 : 0;
  int fast2 = (ws_size >= WS_NEED3) ? 1 : 0;

  hipLaunchKernelGGL(k_init, dim3(K), dim3(256), 0, stream, x, cs, csbf, cspat, fast);
  hipLaunchKernelGGL(k_a2, dim3(B*64), dim3(256), 0, stream, x, a2);
  hipLaunchKernelGGL(k_b2, dim3(B*K), dim3(64), 0, stream, cs, b2);
  if (fast)
    hipLaunchKernelGGL(k_prep, dim3(B*256), dim3(256), 0, stream, x, xbf);
  if (fast2)
    hipLaunchKernelGGL(k_prep2, dim3(B*CPAD*N/8/256), dim3(256), 0, stream, x, xbf2);
  for (int it = 0; it < ITERS; ++it) {
    int last = (it == ITERS-1) ? 1 : 0;
    int wout = (!fast2 || last) ? 1 : 0;   // fp32 Q only needed on last iter in fast2
    if (fast)
      hipLaunchKernelGGL(k_assign2, dim3(B*128), dim3(512), 0, stream,
                         xbf, csbf, cspat, b2, a2, out, qtb, fast2, wout);
    else
      hipLaunchKernelGGL(k_assign, dim3(B*128), dim3(512), 0, stream,
                         x, cs, cspat, b2, a2, out);
    if (split) {
      if (fast2) {
        hipLaunchKernelGGL(k_update5, dim3(B*4*NT), dim3(256), 0, stream,
                           qtb, xbf2, part);
      } else {
        hipLaunchKernelGGL(k_update4, dim3(B*4*NT), dim3(256), 0, stream,
                           x, out, part);
        hipLaunchKernelGGL(k_mass, dim3(B*NTM), dim3(256), 0, stream,
                           out, mpart);
      }
      hipLaunchKernelGGL(k_reduce, dim3(B*200), dim3(256), 0, stream,
                         part, mpart, sacc, macc, spacc, fast2);
    } else {
      hipMemsetAsync(sacc, 0, (size_t)(B*K*C + B*K + B*K*2)*sizeof(float), stream);
      hipLaunchKernelGGL(k_update, dim3(B*512), dim3(256), 0, stream,
                         x, out, sacc, macc, spacc);
    }
    hipLaunchKernelGGL(k_final, dim3(B*K), dim3(256), 0, stream,
                       sacc, macc, spacc, cs, csbf, cspat, b2, outc,
                       last, fast);
  }
}